// Round 7
// baseline (151.856 us; speedup 1.0000x reference)
//
#include <hip/hip_runtime.h>
#include <math.h>

#define GRID_N 256
#define PADN   30
#define GLOB_N 316   // GRID_N + 2*PADN
#define KS     61    // 2*PADN + 1
#define OUT_N  512
#define BATCH  8
#define CHAN   32

// Sampler tile geometry: 128x8 output px per block.
// Deformation bound (analytic, input-independent): pxf in [ox-1.26, ox+1.26],
// pyf in [oy-1.26, oy+1.26]  =>  x0 in [ox-2, ox+1], y0 in [oy-2, oy+1].
// Staged window: rows ty-2 .. ty+9 (12), cols tx-4 .. tx+131 (136).
#define TW     128
#define TH     8
#define SROWS  12
#define SCOLS  136
#define SC4    34            // SCOLS/4
#define NSLOT  (SROWS * SC4) // 408 float4 slots
#define NSLOTPAD 512         // padded so every wave issues 2 full DMA calls
#define BUF_FLOATS (NSLOTPAD * 4)  // 2048 floats = 8 KB per buffer

typedef float v4f __attribute__((ext_vector_type(4)));

#define GLD16(gaddr, laddr)                                                       \
    __builtin_amdgcn_global_load_lds(                                             \
        (const __attribute__((address_space(1))) void*)(gaddr),                   \
        (__attribute__((address_space(3))) void*)(laddr), 16, 0, 0)

// Two 1D Gaussian factor vectors into LDS (first KS threads).
// make_gaussian(a=1,b=0.5,fwhm1=100,fwhm2=25) is exactly separable:
// kernel[u][v] = g1[u]*g1[v] - 0.5*g2[u]*g2[v].
__device__ __forceinline__ void compute_weights(float* w1, float* w2) {
    int t = threadIdx.x;
    if (t < KS) {
        double d  = (double)(t - PADN);
        double r2 = d * d;
        const double c = 2.772588722239781;  // 4*ln(2)
        w1[t] = (float)exp(-c * r2 / 10000.0); // fwhm1 = 100
        w2[t] = (float)exp(-c * r2 / 625.0);   // fwhm2 = 25
    }
}

// Horizontal separable pass. One block per (batch, global row gi in [0,316)).
__global__ __launch_bounds__(256) void hpass_kernel(const float* __restrict__ xs,
                                                    float* __restrict__ H) {
    __shared__ float srow[GLOB_N];
    __shared__ float w1[KS], w2[KS];
    int b  = blockIdx.x / GLOB_N;
    int gi = blockIdx.x % GLOB_N;
    int t  = threadIdx.x;

    compute_weights(w1, w2);

    int iy = gi - PADN;
    iy = iy < 0 ? 0 : (iy > GRID_N - 1 ? GRID_N - 1 : iy);
    const float* src = xs + ((size_t)b * GRID_N + iy) * GRID_N;
    for (int j = t; j < GLOB_N; j += 256) {
        int ix = j - PADN;
        ix = ix < 0 ? 0 : (ix > GRID_N - 1 ? GRID_N - 1 : ix);
        srow[j] = src[ix];
    }
    __syncthreads();

    float a1 = 0.f, a2 = 0.f, a3 = 0.f, a4 = 0.f;
    for (int v = 0; v < KS; ++v) {
        float s  = srow[t + v];
        float cc = (float)(t + v - PADN) * (1.0f / 255.0f);
        float cs = cc * s;
        float cw1 = w1[v], cw2 = w2[v];
        a1 += cw1 * s;
        a2 += cw2 * s;
        a3 += cw1 * cs;
        a4 += cw2 * cs;
    }
    size_t cst  = (size_t)GLOB_N * GRID_N;
    size_t base = ((size_t)(b * 4) * GLOB_N + gi) * GRID_N + t;
    H[base]           = a1;
    H[base + cst]     = a2;
    H[base + 2 * cst] = a3;
    H[base + 3 * cst] = a4;
}

// Vertical pass + normalize + clip. XCD-swizzled (chunk 256 = one batch/XCD).
__global__ __launch_bounds__(256) void vpass_kernel(const float* __restrict__ H,
                                                    float* __restrict__ g256) {
    __shared__ float w1[KS], w2[KS];
    int bid = (int)blockIdx.x;
    bid = (bid & 7) * 256 + (bid >> 3);
    int b = bid >> 8;
    int y = bid & 255;
    int t = threadIdx.x;

    compute_weights(w1, w2);
    __syncthreads();

    const float* Hb = H + (size_t)b * 4 * GLOB_N * GRID_N;
    size_t cst = (size_t)GLOB_N * GRID_N;

    float s1 = 0.f, s2 = 0.f, sx1 = 0.f, sx2 = 0.f, sy1 = 0.f, sy2 = 0.f;
    for (int u = 0; u < KS; ++u) {
        size_t off = (size_t)(y + u) * GRID_N + t;
        float h1 = Hb[off];
        float h2 = Hb[off + cst];
        float h3 = Hb[off + 2 * cst];
        float h4 = Hb[off + 3 * cst];
        float cw1 = w1[u], cw2 = w2[u];
        float cc = (float)(y + u - PADN) * (1.0f / 255.0f);
        s1  += cw1 * h1;
        s2  += cw2 * h2;
        sx1 += cw1 * h3;
        sx2 += cw2 * h4;
        sy1 += cw1 * (cc * h1);
        sy2 += cw2 * (cc * h2);
    }
    float p  = s1 - 0.5f * s2;
    float xf = (sx1 - 0.5f * sx2) / p;
    float yf = (sy1 - 0.5f * sy2) / p;
    float xg = fminf(fmaxf(xf * 2.0f - 1.0f, -1.0f), 1.0f);
    float yg = fminf(fmaxf(yf * 2.0f - 1.0f, -1.0f), 1.0f);

    size_t o = (size_t)(b * 2) * GRID_N * GRID_N + (size_t)y * GRID_N + t;
    g256[o] = xg;
    g256[o + (size_t)GRID_N * GRID_N] = yg;
}

// 2x bilinear upsample (fallback path when ws is too small to hold g256).
__global__ __launch_bounds__(256) void upsample_kernel(const float* __restrict__ g256,
                                                       float* __restrict__ gup) {
    int idx = blockIdx.x * 256 + threadIdx.x;
    int ox = idx & (OUT_N - 1);
    int oy = (idx >> 9) & (OUT_N - 1);
    int b  = idx >> 18;

    float sx = 0.5f * (float)ox - 0.25f;
    float sy = 0.5f * (float)oy - 0.25f;
    float fxf = floorf(sx), fyf = floorf(sy);
    int x0 = (int)fxf, y0 = (int)fyf;
    float fx = sx - fxf, fy = sy - fyf;
    int x0c = x0 < 0 ? 0 : x0;
    int x1c = x0 + 1 > GRID_N - 1 ? GRID_N - 1 : x0 + 1;
    int y0c = y0 < 0 ? 0 : y0;
    int y1c = y0 + 1 > GRID_N - 1 ? GRID_N - 1 : y0 + 1;

    for (int c = 0; c < 2; ++c) {
        const float* g = g256 + ((size_t)(b * 2 + c)) * GRID_N * GRID_N;
        float v00 = g[y0c * GRID_N + x0c];
        float v10 = g[y0c * GRID_N + x1c];
        float v01 = g[y1c * GRID_N + x0c];
        float v11 = g[y1c * GRID_N + x1c];
        float v = (v00 * (1.f - fx) + v10 * fx) * (1.f - fy)
                + (v01 * (1.f - fx) + v11 * fx) * fy;
        gup[((size_t)(b * 2 + c)) * OUT_N * OUT_N + (size_t)oy * OUT_N + ox] = v;
    }
}

// grid_sample bilinear via DMA-staged LDS tiles (global_load_lds), ping-pong
// buffers, counted vmcnt + raw barriers: loads for channel c+1/c+2 stay in
// flight across barriers (never drained to 0 mid-loop).
template <int FUSED>
__global__ __launch_bounds__(256) void sample_kernel(const float* __restrict__ x,
                                                     const float* __restrict__ g256,
                                                     const float* __restrict__ gup_in,
                                                     float* __restrict__ gup_out,
                                                     float* __restrict__ out) {
    __shared__ float tile[2 * BUF_FLOATS];   // 16 KB

    int bid = (int)blockIdx.x;
    bid = (bid & 7) * 256 + (bid >> 3);
    int b  = bid >> 8;          // 256 tiles per batch
    int tb = bid & 255;
    int tx = (tb & 3) * TW;
    int ty = (tb >> 2) * TH;

    int t   = threadIdx.x;
    int col = t & (TW - 1);
    int kk  = t >> 7;           // 0 or 1

    int row_base = ty - 2;
    int col_base = tx - 4;

    // ---- per-thread DMA source offsets (channel-invariant) ----
    // slot k -> LDS float offset k*4 (linear in k => matches global_load_lds
    // wave-uniform-base + lane*16 layout). Source clamped to image.
    int offA, offB;
    {
        int k = t;
        int r = k / SC4, i = k - r * SC4;
        int rg = row_base + r; rg = rg < 0 ? 0 : (rg > OUT_N - 1 ? OUT_N - 1 : rg);
        int cg = col_base + i * 4; cg = cg < 0 ? 0 : (cg > OUT_N - 4 ? OUT_N - 4 : cg);
        offA = rg * OUT_N + cg;
        offB = offA;             // pad lanes (slot >= NSLOT) load harmlessly
        k = t + 256;
        if (k < NSLOT) {
            r = k / SC4; i = k - r * SC4;
            rg = row_base + r; rg = rg < 0 ? 0 : (rg > OUT_N - 1 ? OUT_N - 1 : rg);
            cg = col_base + i * 4; cg = cg < 0 ? 0 : (cg > OUT_N - 4 ? OUT_N - 4 : cg);
            offB = rg * OUT_N + cg;
        }
    }
    int wbase = (t & ~63) * 4;   // wave-uniform float offset of this wave's call-1 region

    // ---- per-px bilinear weights + LDS base indices (channel-invariant) ----
    float w00[4], w10[4], w01[4], w11[4];
    int lbase[4];
    {
        int ox = tx + col;
        float bx = -1.0f + (float)ox * (2.0f / 511.0f);

        float usx = 0.5f * (float)ox - 0.25f;
        float ufxf = floorf(usx);
        int ux0 = (int)ufxf;
        float ufx = usx - ufxf;
        int ux0c = ux0 < 0 ? 0 : ux0;
        int ux1c = ux0 + 1 > GRID_N - 1 ? GRID_N - 1 : ux0 + 1;
        const float* g0 = g256 + (size_t)(b * 2) * GRID_N * GRID_N;
        const float* g1 = g0 + GRID_N * GRID_N;
        size_t gplane = (size_t)OUT_N * OUT_N;

        #pragma unroll
        for (int j = 0; j < 4; ++j) {
            int oy = ty + kk + 2 * j;
            float gxu, gyu;
            if (FUSED) {
                float usy = 0.5f * (float)oy - 0.25f;
                float ufyf = floorf(usy);
                int uy0 = (int)ufyf;
                float ufy = usy - ufyf;
                int uy0c = uy0 < 0 ? 0 : uy0;
                int uy1c = uy0 + 1 > GRID_N - 1 ? GRID_N - 1 : uy0 + 1;
                {
                    float v00 = g0[uy0c * GRID_N + ux0c];
                    float v10 = g0[uy0c * GRID_N + ux1c];
                    float v01 = g0[uy1c * GRID_N + ux0c];
                    float v11 = g0[uy1c * GRID_N + ux1c];
                    gxu = (v00 * (1.f - ufx) + v10 * ufx) * (1.f - ufy)
                        + (v01 * (1.f - ufx) + v11 * ufx) * ufy;
                }
                {
                    float v00 = g1[uy0c * GRID_N + ux0c];
                    float v10 = g1[uy0c * GRID_N + ux1c];
                    float v01 = g1[uy1c * GRID_N + ux0c];
                    float v11 = g1[uy1c * GRID_N + ux1c];
                    gyu = (v00 * (1.f - ufx) + v10 * ufx) * (1.f - ufy)
                        + (v01 * (1.f - ufx) + v11 * ufx) * ufy;
                }
                size_t gidx = (size_t)(b * 2) * gplane + (size_t)oy * OUT_N + ox;
                __builtin_nontemporal_store(gxu, gup_out + gidx);
                __builtin_nontemporal_store(gyu, gup_out + gidx + gplane);
            } else {
                size_t gidx = (size_t)(b * 2) * gplane + (size_t)oy * OUT_N + ox;
                gxu = gup_in[gidx];
                gyu = gup_in[gidx + gplane];
            }

            float by = -1.0f + (float)oy * (2.0f / 511.0f);
            float gx = (49.0f * bx + gxu) * 0.02f;
            float gy = (49.0f * by + gyu) * 0.02f;
            float pxf = (gx + 1.0f) * 255.5f;  // in [0,511]
            float pyf = (gy + 1.0f) * 255.5f;
            float fx0 = floorf(pxf), fy0 = floorf(pyf);
            int x0 = (int)fx0, y0 = (int)fy0;
            float fx = pxf - fx0, fy = pyf - fy0;
            w00[j] = (1.f - fx) * (1.f - fy);
            w10[j] = fx * (1.f - fy);
            w01[j] = (1.f - fx) * fy;
            w11[j] = fx * fy;
            lbase[j] = (y0 - row_base) * SCOLS + (x0 - col_base);
        }
    }

    size_t plane = (size_t)OUT_N * OUT_N;
    const float* xb = x + (size_t)b * CHAN * plane;
    float* ob = out + (size_t)b * CHAN * plane;
    int ocol = tx + col;

    #define STAGE(c, bufIdx)                                                     \
        do {                                                                     \
            const float* xc_ = xb + (size_t)(c) * plane;                         \
            GLD16(xc_ + offA, &tile[(bufIdx) * BUF_FLOATS + wbase]);             \
            GLD16(xc_ + offB, &tile[(bufIdx) * BUF_FLOATS + 1024 + wbase]);      \
        } while (0)

    STAGE(0, 0);
    STAGE(1, 1);

    float v[4];
    for (int c = 0; c < CHAN; ++c) {
        // counted wait: this channel's 2 DMA loads are the oldest outstanding
        // besides (c+1)'s 2 loads (+4 stores issued after them mid-loop).
        if (c == 0)            asm volatile("s_waitcnt vmcnt(2)" ::: "memory");
        else if (c == CHAN - 1) asm volatile("s_waitcnt vmcnt(4)" ::: "memory");
        else                    asm volatile("s_waitcnt vmcnt(6)" ::: "memory");
        __builtin_amdgcn_s_barrier();          // all waves' c-loads landed
        __builtin_amdgcn_sched_barrier(0);

        const float* tb_ = &tile[(c & 1) * BUF_FLOATS];
        #pragma unroll
        for (int j = 0; j < 4; ++j) {
            int lb = lbase[j];
            float v00 = tb_[lb];
            float v10 = tb_[lb + 1];
            float v01 = tb_[lb + SCOLS];
            float v11 = tb_[lb + SCOLS + 1];
            v[j] = w00[j] * v00 + w10[j] * v10 + w01[j] * v01 + w11[j] * v11;
        }

        __builtin_amdgcn_sched_barrier(0);
        __builtin_amdgcn_s_barrier();          // all waves done reading buf[c&1]
        __builtin_amdgcn_sched_barrier(0);

        if (c + 2 < CHAN) STAGE(c + 2, c & 1); // DMA overwrite is now safe

        float* oc = ob + (size_t)c * plane;
        #pragma unroll
        for (int j = 0; j < 4; ++j) {
            int oy = ty + kk + 2 * j;
            __builtin_nontemporal_store(v[j], oc + (size_t)oy * OUT_N + ocol);
        }
    }
    #undef STAGE
}

extern "C" void kernel_launch(void* const* d_in, const int* in_sizes, int n_in,
                              void* d_out, int out_size, void* d_ws, size_t ws_size,
                              hipStream_t stream) {
    (void)in_sizes; (void)n_in; (void)out_size;
    const float* x  = (const float*)d_in[0];   // (8,32,512,512)
    const float* xs = (const float*)d_in[1];   // (8,1,256,256)
    // d_in[2] = gauss_kernel: recomputed analytically (separable form).

    float* out = (float*)d_out;
    const size_t XS_OUT = (size_t)BATCH * CHAN * OUT_N * OUT_N;  // 67,108,864
    float* gup = out + XS_OUT;  // output 1: grid_up (8,2,512,512)

    // H always lives in the x_sampled region (consumed by vpass before the
    // sampler runs). g256 must survive into the sampler, so it goes to d_ws
    // when possible; otherwise fall back to the gup-reading sampler.
    float* H = out;                            // 8*4*316*256 floats
    const size_t G256_BYTES = (size_t)BATCH * 2 * GRID_N * GRID_N * sizeof(float);
    bool fused = ws_size >= G256_BYTES;
    float* g256 = fused ? (float*)d_ws : out + 4u * 1024 * 1024;

    hipLaunchKernelGGL(hpass_kernel, dim3(BATCH * GLOB_N), dim3(256), 0, stream, xs, H);
    hipLaunchKernelGGL(vpass_kernel, dim3(BATCH * GRID_N), dim3(256), 0, stream, H, g256);
    if (fused) {
        hipLaunchKernelGGL((sample_kernel<1>), dim3(BATCH * OUT_N * OUT_N / (TW * TH)),
                           dim3(256), 0, stream, x, g256, gup, gup, out);
    } else {
        hipLaunchKernelGGL(upsample_kernel, dim3(BATCH * OUT_N * OUT_N / 256), dim3(256), 0,
                           stream, g256, gup);
        hipLaunchKernelGGL((sample_kernel<0>), dim3(BATCH * OUT_N * OUT_N / (TW * TH)),
                           dim3(256), 0, stream, x, g256, gup, gup, out);
    }
}

// Round 8
// 147.355 us; speedup vs baseline: 1.0305x; 1.0305x over previous
//
#include <hip/hip_runtime.h>
#include <math.h>

#define GRID_N 256
#define PADN   30
#define GLOB_N 316   // GRID_N + 2*PADN
#define KS     61    // 2*PADN + 1
#define OUT_N  512
#define BATCH  8
#define CHAN   32
#define CPB    8     // channels per sampler block (32/CPB channel-groups)

// Sampler tile geometry: 128x8 output px per block.
// Deformation bound (analytic, input-independent): pxf in [ox-1.26, ox+1.26],
// pyf in [oy-1.26, oy+1.26]  =>  x0 in [ox-2, ox+1], y0 in [oy-2, oy+1].
// Staged window: rows ty-2 .. ty+9 (12), cols tx-4 .. tx+131 (136).
#define TW     128
#define TH     8
#define SROWS  12
#define SCOLS  136
#define SC4    34            // SCOLS/4
#define NSLOT  (SROWS * SC4) // 408 float4 slots
#define NSLOTPAD 512         // padded so every wave issues 2 full DMA calls
#define BUF_FLOATS (NSLOTPAD * 4)  // 2048 floats = 8 KB per buffer

typedef float v4f __attribute__((ext_vector_type(4)));

#define GLD16(gaddr, laddr)                                                       \
    __builtin_amdgcn_global_load_lds(                                             \
        (const __attribute__((address_space(1))) void*)(gaddr),                   \
        (__attribute__((address_space(3))) void*)(laddr), 16, 0, 0)

// Two 1D Gaussian factor vectors into LDS (first KS threads).
// make_gaussian(a=1,b=0.5,fwhm1=100,fwhm2=25) is exactly separable:
// kernel[u][v] = g1[u]*g1[v] - 0.5*g2[u]*g2[v].
__device__ __forceinline__ void compute_weights(float* w1, float* w2) {
    int t = threadIdx.x;
    if (t < KS) {
        double d  = (double)(t - PADN);
        double r2 = d * d;
        const double c = 2.772588722239781;  // 4*ln(2)
        w1[t] = (float)exp(-c * r2 / 10000.0); // fwhm1 = 100
        w2[t] = (float)exp(-c * r2 / 625.0);   // fwhm2 = 25
    }
}

// Horizontal separable pass. One block per (batch, global row gi in [0,316)).
__global__ __launch_bounds__(256) void hpass_kernel(const float* __restrict__ xs,
                                                    float* __restrict__ H) {
    __shared__ float srow[GLOB_N];
    __shared__ float w1[KS], w2[KS];
    int b  = blockIdx.x / GLOB_N;
    int gi = blockIdx.x % GLOB_N;
    int t  = threadIdx.x;

    compute_weights(w1, w2);

    int iy = gi - PADN;
    iy = iy < 0 ? 0 : (iy > GRID_N - 1 ? GRID_N - 1 : iy);
    const float* src = xs + ((size_t)b * GRID_N + iy) * GRID_N;
    for (int j = t; j < GLOB_N; j += 256) {
        int ix = j - PADN;
        ix = ix < 0 ? 0 : (ix > GRID_N - 1 ? GRID_N - 1 : ix);
        srow[j] = src[ix];
    }
    __syncthreads();

    float a1 = 0.f, a2 = 0.f, a3 = 0.f, a4 = 0.f;
    for (int v = 0; v < KS; ++v) {
        float s  = srow[t + v];
        float cc = (float)(t + v - PADN) * (1.0f / 255.0f);
        float cs = cc * s;
        float cw1 = w1[v], cw2 = w2[v];
        a1 += cw1 * s;
        a2 += cw2 * s;
        a3 += cw1 * cs;
        a4 += cw2 * cs;
    }
    size_t cst  = (size_t)GLOB_N * GRID_N;
    size_t base = ((size_t)(b * 4) * GLOB_N + gi) * GRID_N + t;
    H[base]           = a1;
    H[base + cst]     = a2;
    H[base + 2 * cst] = a3;
    H[base + 3 * cst] = a4;
}

// Vertical pass + normalize + clip. XCD-swizzled (chunk 256 = one batch/XCD).
__global__ __launch_bounds__(256) void vpass_kernel(const float* __restrict__ H,
                                                    float* __restrict__ g256) {
    __shared__ float w1[KS], w2[KS];
    int bid = (int)blockIdx.x;
    bid = (bid & 7) * 256 + (bid >> 3);
    int b = bid >> 8;
    int y = bid & 255;
    int t = threadIdx.x;

    compute_weights(w1, w2);
    __syncthreads();

    const float* Hb = H + (size_t)b * 4 * GLOB_N * GRID_N;
    size_t cst = (size_t)GLOB_N * GRID_N;

    float s1 = 0.f, s2 = 0.f, sx1 = 0.f, sx2 = 0.f, sy1 = 0.f, sy2 = 0.f;
    for (int u = 0; u < KS; ++u) {
        size_t off = (size_t)(y + u) * GRID_N + t;
        float h1 = Hb[off];
        float h2 = Hb[off + cst];
        float h3 = Hb[off + 2 * cst];
        float h4 = Hb[off + 3 * cst];
        float cw1 = w1[u], cw2 = w2[u];
        float cc = (float)(y + u - PADN) * (1.0f / 255.0f);
        s1  += cw1 * h1;
        s2  += cw2 * h2;
        sx1 += cw1 * h3;
        sx2 += cw2 * h4;
        sy1 += cw1 * (cc * h1);
        sy2 += cw2 * (cc * h2);
    }
    float p  = s1 - 0.5f * s2;
    float xf = (sx1 - 0.5f * sx2) / p;
    float yf = (sy1 - 0.5f * sy2) / p;
    float xg = fminf(fmaxf(xf * 2.0f - 1.0f, -1.0f), 1.0f);
    float yg = fminf(fmaxf(yf * 2.0f - 1.0f, -1.0f), 1.0f);

    size_t o = (size_t)(b * 2) * GRID_N * GRID_N + (size_t)y * GRID_N + t;
    g256[o] = xg;
    g256[o + (size_t)GRID_N * GRID_N] = yg;
}

// 2x bilinear upsample (fallback path when ws is too small to hold g256).
__global__ __launch_bounds__(256) void upsample_kernel(const float* __restrict__ g256,
                                                       float* __restrict__ gup) {
    int idx = blockIdx.x * 256 + threadIdx.x;
    int ox = idx & (OUT_N - 1);
    int oy = (idx >> 9) & (OUT_N - 1);
    int b  = idx >> 18;

    float sx = 0.5f * (float)ox - 0.25f;
    float sy = 0.5f * (float)oy - 0.25f;
    float fxf = floorf(sx), fyf = floorf(sy);
    int x0 = (int)fxf, y0 = (int)fyf;
    float fx = sx - fxf, fy = sy - fyf;
    int x0c = x0 < 0 ? 0 : x0;
    int x1c = x0 + 1 > GRID_N - 1 ? GRID_N - 1 : x0 + 1;
    int y0c = y0 < 0 ? 0 : y0;
    int y1c = y0 + 1 > GRID_N - 1 ? GRID_N - 1 : y0 + 1;

    for (int c = 0; c < 2; ++c) {
        const float* g = g256 + ((size_t)(b * 2 + c)) * GRID_N * GRID_N;
        float v00 = g[y0c * GRID_N + x0c];
        float v10 = g[y0c * GRID_N + x1c];
        float v01 = g[y1c * GRID_N + x0c];
        float v11 = g[y1c * GRID_N + x1c];
        float v = (v00 * (1.f - fx) + v10 * fx) * (1.f - fy)
                + (v01 * (1.f - fx) + v11 * fx) * fy;
        gup[((size_t)(b * 2 + c)) * OUT_N * OUT_N + (size_t)oy * OUT_N + ox] = v;
    }
}

// grid_sample bilinear via DMA-staged LDS tiles. Each block handles CPB=8
// channels of one 128x8 tile (4x shorter serial channel chain than R6;
// 4x more independent pipelines per CU so one block's HBM stage overlaps
// another's LDS gather). gup written only by channel-group 0.
template <int FUSED>
__global__ __launch_bounds__(256) void sample_kernel(const float* __restrict__ x,
                                                     const float* __restrict__ g256,
                                                     const float* __restrict__ gup_in,
                                                     float* __restrict__ gup_out,
                                                     float* __restrict__ out) {
    __shared__ float tile[2 * BUF_FLOATS];   // 16 KB

    int bid = (int)blockIdx.x;
    // 8192 blocks; chunk 1024 -> XCD k owns batch k.
    bid = (bid & 7) * 1024 + (bid >> 3);
    int b  = bid >> 10;          // 1024 blocks per batch
    int r10 = bid & 1023;
    int cg = r10 >> 8;           // channel group 0..3 (slow -> tile locality)
    int tb = r10 & 255;
    int tx = (tb & 3) * TW;
    int ty = (tb >> 2) * TH;
    int c0 = cg * CPB;

    int t   = threadIdx.x;
    int col = t & (TW - 1);
    int kk  = t >> 7;           // 0 or 1

    int row_base = ty - 2;
    int col_base = tx - 4;

    // ---- per-thread DMA source offsets (channel-invariant) ----
    int offA, offB;
    {
        int k = t;
        int r = k / SC4, i = k - r * SC4;
        int rg = row_base + r; rg = rg < 0 ? 0 : (rg > OUT_N - 1 ? OUT_N - 1 : rg);
        int cg2 = col_base + i * 4; cg2 = cg2 < 0 ? 0 : (cg2 > OUT_N - 4 ? OUT_N - 4 : cg2);
        offA = rg * OUT_N + cg2;
        offB = offA;             // pad lanes (slot >= NSLOT) load harmlessly
        k = t + 256;
        if (k < NSLOT) {
            r = k / SC4; i = k - r * SC4;
            rg = row_base + r; rg = rg < 0 ? 0 : (rg > OUT_N - 1 ? OUT_N - 1 : rg);
            cg2 = col_base + i * 4; cg2 = cg2 < 0 ? 0 : (cg2 > OUT_N - 4 ? OUT_N - 4 : cg2);
            offB = rg * OUT_N + cg2;
        }
    }
    int wbase = (t & ~63) * 4;   // wave-uniform float offset of this wave's region

    // ---- per-px bilinear weights + LDS base indices (channel-invariant) ----
    float w00[4], w10[4], w01[4], w11[4];
    int lbase[4];
    {
        int ox = tx + col;
        float bx = -1.0f + (float)ox * (2.0f / 511.0f);

        float usx = 0.5f * (float)ox - 0.25f;
        float ufxf = floorf(usx);
        int ux0 = (int)ufxf;
        float ufx = usx - ufxf;
        int ux0c = ux0 < 0 ? 0 : ux0;
        int ux1c = ux0 + 1 > GRID_N - 1 ? GRID_N - 1 : ux0 + 1;
        const float* g0 = g256 + (size_t)(b * 2) * GRID_N * GRID_N;
        const float* g1 = g0 + GRID_N * GRID_N;
        size_t gplane = (size_t)OUT_N * OUT_N;

        #pragma unroll
        for (int j = 0; j < 4; ++j) {
            int oy = ty + kk + 2 * j;
            float gxu, gyu;
            if (FUSED) {
                float usy = 0.5f * (float)oy - 0.25f;
                float ufyf = floorf(usy);
                int uy0 = (int)ufyf;
                float ufy = usy - ufyf;
                int uy0c = uy0 < 0 ? 0 : uy0;
                int uy1c = uy0 + 1 > GRID_N - 1 ? GRID_N - 1 : uy0 + 1;
                {
                    float v00 = g0[uy0c * GRID_N + ux0c];
                    float v10 = g0[uy0c * GRID_N + ux1c];
                    float v01 = g0[uy1c * GRID_N + ux0c];
                    float v11 = g0[uy1c * GRID_N + ux1c];
                    gxu = (v00 * (1.f - ufx) + v10 * ufx) * (1.f - ufy)
                        + (v01 * (1.f - ufx) + v11 * ufx) * ufy;
                }
                {
                    float v00 = g1[uy0c * GRID_N + ux0c];
                    float v10 = g1[uy0c * GRID_N + ux1c];
                    float v01 = g1[uy1c * GRID_N + ux0c];
                    float v11 = g1[uy1c * GRID_N + ux1c];
                    gyu = (v00 * (1.f - ufx) + v10 * ufx) * (1.f - ufy)
                        + (v01 * (1.f - ufx) + v11 * ufx) * ufy;
                }
                if (cg == 0) {
                    size_t gidx = (size_t)(b * 2) * gplane + (size_t)oy * OUT_N + ox;
                    __builtin_nontemporal_store(gxu, gup_out + gidx);
                    __builtin_nontemporal_store(gyu, gup_out + gidx + gplane);
                }
            } else {
                size_t gidx = (size_t)(b * 2) * gplane + (size_t)oy * OUT_N + ox;
                gxu = gup_in[gidx];
                gyu = gup_in[gidx + gplane];
            }

            float by = -1.0f + (float)oy * (2.0f / 511.0f);
            float gx = (49.0f * bx + gxu) * 0.02f;
            float gy = (49.0f * by + gyu) * 0.02f;
            float pxf = (gx + 1.0f) * 255.5f;  // in [0,511]
            float pyf = (gy + 1.0f) * 255.5f;
            float fx0 = floorf(pxf), fy0 = floorf(pyf);
            int x0 = (int)fx0, y0 = (int)fy0;
            float fx = pxf - fx0, fy = pyf - fy0;
            w00[j] = (1.f - fx) * (1.f - fy);
            w10[j] = fx * (1.f - fy);
            w01[j] = (1.f - fx) * fy;
            w11[j] = fx * fy;
            lbase[j] = (y0 - row_base) * SCOLS + (x0 - col_base);
        }
    }

    size_t plane = (size_t)OUT_N * OUT_N;
    const float* xb = x + ((size_t)b * CHAN + c0) * plane;
    float* ob = out + ((size_t)b * CHAN + c0) * plane;
    int ocol = tx + col;

    #define STAGE(c, bufIdx)                                                     \
        do {                                                                     \
            const float* xc_ = xb + (size_t)(c) * plane;                         \
            GLD16(xc_ + offA, &tile[(bufIdx) * BUF_FLOATS + wbase]);             \
            GLD16(xc_ + offB, &tile[(bufIdx) * BUF_FLOATS + 1024 + wbase]);      \
        } while (0)

    STAGE(0, 0);
    STAGE(1, 1);

    float v[4];
    for (int c = 0; c < CPB; ++c) {
        // counted wait: steady state has loads(c+1) [2] + stores(c-1) [4]
        // younger than loads(c) -> vmcnt(6); first iter only loads(1) -> 2;
        // last iter only stores(c-1) -> 4.
        if (c == 0)            asm volatile("s_waitcnt vmcnt(2)" ::: "memory");
        else if (c == CPB - 1) asm volatile("s_waitcnt vmcnt(4)" ::: "memory");
        else                    asm volatile("s_waitcnt vmcnt(6)" ::: "memory");
        __builtin_amdgcn_s_barrier();          // all waves' c-loads landed
        __builtin_amdgcn_sched_barrier(0);

        const float* tb_ = &tile[(c & 1) * BUF_FLOATS];
        #pragma unroll
        for (int j = 0; j < 4; ++j) {
            int lb = lbase[j];
            float v00 = tb_[lb];
            float v10 = tb_[lb + 1];
            float v01 = tb_[lb + SCOLS];
            float v11 = tb_[lb + SCOLS + 1];
            v[j] = w00[j] * v00 + w10[j] * v10 + w01[j] * v01 + w11[j] * v11;
        }

        __builtin_amdgcn_sched_barrier(0);
        __builtin_amdgcn_s_barrier();          // all waves done reading buf[c&1]
        __builtin_amdgcn_sched_barrier(0);

        if (c + 2 < CPB) STAGE(c + 2, c & 1);  // DMA overwrite now safe

        float* oc = ob + (size_t)c * plane;
        #pragma unroll
        for (int j = 0; j < 4; ++j) {
            int oy = ty + kk + 2 * j;
            __builtin_nontemporal_store(v[j], oc + (size_t)oy * OUT_N + ocol);
        }
    }
    #undef STAGE
}

extern "C" void kernel_launch(void* const* d_in, const int* in_sizes, int n_in,
                              void* d_out, int out_size, void* d_ws, size_t ws_size,
                              hipStream_t stream) {
    (void)in_sizes; (void)n_in; (void)out_size;
    const float* x  = (const float*)d_in[0];   // (8,32,512,512)
    const float* xs = (const float*)d_in[1];   // (8,1,256,256)
    // d_in[2] = gauss_kernel: recomputed analytically (separable form).

    float* out = (float*)d_out;
    const size_t XS_OUT = (size_t)BATCH * CHAN * OUT_N * OUT_N;  // 67,108,864
    float* gup = out + XS_OUT;  // output 1: grid_up (8,2,512,512)

    // H always lives in the x_sampled region (consumed by vpass before the
    // sampler runs). g256 must survive into the sampler, so it goes to d_ws
    // when possible; otherwise fall back to the gup-reading sampler.
    float* H = out;                            // 8*4*316*256 floats
    const size_t G256_BYTES = (size_t)BATCH * 2 * GRID_N * GRID_N * sizeof(float);
    bool fused = ws_size >= G256_BYTES;
    float* g256 = fused ? (float*)d_ws : out + 4u * 1024 * 1024;

    hipLaunchKernelGGL(hpass_kernel, dim3(BATCH * GLOB_N), dim3(256), 0, stream, xs, H);
    hipLaunchKernelGGL(vpass_kernel, dim3(BATCH * GRID_N), dim3(256), 0, stream, H, g256);
    const int SBLOCKS = BATCH * (CHAN / CPB) * (OUT_N * OUT_N / (TW * TH));
    if (fused) {
        hipLaunchKernelGGL((sample_kernel<1>), dim3(SBLOCKS), dim3(256), 0, stream,
                           x, g256, gup, gup, out);
    } else {
        hipLaunchKernelGGL(upsample_kernel, dim3(BATCH * OUT_N * OUT_N / 256), dim3(256), 0,
                           stream, g256, gup);
        hipLaunchKernelGGL((sample_kernel<0>), dim3(SBLOCKS), dim3(256), 0, stream,
                           x, g256, gup, gup, out);
    }
}

// Round 9
// 138.859 us; speedup vs baseline: 1.0936x; 1.0612x over previous
//
#include <hip/hip_runtime.h>
#include <math.h>

#define GRID_N 256
#define PADN   30
#define GLOB_N 316   // GRID_N + 2*PADN
#define KS     61    // 2*PADN + 1
#define OUT_N  512
#define BATCH  8
#define CHAN   32
#define CPB    8     // channels per sampler block

// Sampler tile: 4 full-width output rows (4x512) per block, CPB channels.
// Deformation bound (analytic, input-independent): pyf in [oy-1.26, oy+1.26],
// gx,gy in [-1,1] => y0 in [oy-2, oy+1], x0 in [0,511].
// Staged window: rows ty-2..ty+5 (8 rows x 512 cols = 16 KB, CONTIGUOUS).
#define STH    4                  // output rows per block
#define SSR    8                  // staged rows
#define SCOLS  512
#define SLOTS  1024               // float4 slots per buffer (= SSR*SCOLS/4)
#define BUFS   4160               // floats per buffer incl. 64-float pad
// LDS: 2*BUFS*4 = 33,280 B -> 4 blocks/CU

typedef float v2f __attribute__((ext_vector_type(2)));

#define GLD16(gaddr, laddr)                                                       \
    __builtin_amdgcn_global_load_lds(                                             \
        (const __attribute__((address_space(1))) void*)(gaddr),                   \
        (__attribute__((address_space(3))) void*)(laddr), 16, 0, 0)

// Two 1D Gaussian factor vectors into LDS (first KS threads).
// make_gaussian(a=1,b=0.5,fwhm1=100,fwhm2=25) is exactly separable:
// kernel[u][v] = g1[u]*g1[v] - 0.5*g2[u]*g2[v].
__device__ __forceinline__ void compute_weights(float* w1, float* w2) {
    int t = threadIdx.x;
    if (t < KS) {
        double d  = (double)(t - PADN);
        double r2 = d * d;
        const double c = 2.772588722239781;  // 4*ln(2)
        w1[t] = (float)exp(-c * r2 / 10000.0); // fwhm1 = 100
        w2[t] = (float)exp(-c * r2 / 625.0);   // fwhm2 = 25
    }
}

// Horizontal separable pass. One block per (batch, global row gi in [0,316)).
__global__ __launch_bounds__(256) void hpass_kernel(const float* __restrict__ xs,
                                                    float* __restrict__ H) {
    __shared__ float srow[GLOB_N];
    __shared__ float w1[KS], w2[KS];
    int b  = blockIdx.x / GLOB_N;
    int gi = blockIdx.x % GLOB_N;
    int t  = threadIdx.x;

    compute_weights(w1, w2);

    int iy = gi - PADN;
    iy = iy < 0 ? 0 : (iy > GRID_N - 1 ? GRID_N - 1 : iy);
    const float* src = xs + ((size_t)b * GRID_N + iy) * GRID_N;
    for (int j = t; j < GLOB_N; j += 256) {
        int ix = j - PADN;
        ix = ix < 0 ? 0 : (ix > GRID_N - 1 ? GRID_N - 1 : ix);
        srow[j] = src[ix];
    }
    __syncthreads();

    float a1 = 0.f, a2 = 0.f, a3 = 0.f, a4 = 0.f;
    for (int v = 0; v < KS; ++v) {
        float s  = srow[t + v];
        float cc = (float)(t + v - PADN) * (1.0f / 255.0f);
        float cs = cc * s;
        float cw1 = w1[v], cw2 = w2[v];
        a1 += cw1 * s;
        a2 += cw2 * s;
        a3 += cw1 * cs;
        a4 += cw2 * cs;
    }
    size_t cst  = (size_t)GLOB_N * GRID_N;
    size_t base = ((size_t)(b * 4) * GLOB_N + gi) * GRID_N + t;
    H[base]           = a1;
    H[base + cst]     = a2;
    H[base + 2 * cst] = a3;
    H[base + 3 * cst] = a4;
}

// Vertical pass + normalize + clip. XCD-swizzled (chunk 256 = one batch/XCD).
__global__ __launch_bounds__(256) void vpass_kernel(const float* __restrict__ H,
                                                    float* __restrict__ g256) {
    __shared__ float w1[KS], w2[KS];
    int bid = (int)blockIdx.x;
    bid = (bid & 7) * 256 + (bid >> 3);
    int b = bid >> 8;
    int y = bid & 255;
    int t = threadIdx.x;

    compute_weights(w1, w2);
    __syncthreads();

    const float* Hb = H + (size_t)b * 4 * GLOB_N * GRID_N;
    size_t cst = (size_t)GLOB_N * GRID_N;

    float s1 = 0.f, s2 = 0.f, sx1 = 0.f, sx2 = 0.f, sy1 = 0.f, sy2 = 0.f;
    for (int u = 0; u < KS; ++u) {
        size_t off = (size_t)(y + u) * GRID_N + t;
        float h1 = Hb[off];
        float h2 = Hb[off + cst];
        float h3 = Hb[off + 2 * cst];
        float h4 = Hb[off + 3 * cst];
        float cw1 = w1[u], cw2 = w2[u];
        float cc = (float)(y + u - PADN) * (1.0f / 255.0f);
        s1  += cw1 * h1;
        s2  += cw2 * h2;
        sx1 += cw1 * h3;
        sx2 += cw2 * h4;
        sy1 += cw1 * (cc * h1);
        sy2 += cw2 * (cc * h2);
    }
    float p  = s1 - 0.5f * s2;
    float xf = (sx1 - 0.5f * sx2) / p;
    float yf = (sy1 - 0.5f * sy2) / p;
    float xg = fminf(fmaxf(xf * 2.0f - 1.0f, -1.0f), 1.0f);
    float yg = fminf(fmaxf(yf * 2.0f - 1.0f, -1.0f), 1.0f);

    size_t o = (size_t)(b * 2) * GRID_N * GRID_N + (size_t)y * GRID_N + t;
    g256[o] = xg;
    g256[o + (size_t)GRID_N * GRID_N] = yg;
}

// 2x bilinear upsample, jax.image.resize half-pixel semantics.
__global__ __launch_bounds__(256) void upsample_kernel(const float* __restrict__ g256,
                                                       float* __restrict__ gup) {
    int idx = blockIdx.x * 256 + threadIdx.x;
    int ox = idx & (OUT_N - 1);
    int oy = (idx >> 9) & (OUT_N - 1);
    int b  = idx >> 18;

    float sx = 0.5f * (float)ox - 0.25f;
    float sy = 0.5f * (float)oy - 0.25f;
    float fxf = floorf(sx), fyf = floorf(sy);
    int x0 = (int)fxf, y0 = (int)fyf;
    float fx = sx - fxf, fy = sy - fyf;
    int x0c = x0 < 0 ? 0 : x0;
    int x1c = x0 + 1 > GRID_N - 1 ? GRID_N - 1 : x0 + 1;
    int y0c = y0 < 0 ? 0 : y0;
    int y1c = y0 + 1 > GRID_N - 1 ? GRID_N - 1 : y0 + 1;

    for (int c = 0; c < 2; ++c) {
        const float* g = g256 + ((size_t)(b * 2 + c)) * GRID_N * GRID_N;
        float v00 = g[y0c * GRID_N + x0c];
        float v10 = g[y0c * GRID_N + x1c];
        float v01 = g[y1c * GRID_N + x0c];
        float v11 = g[y1c * GRID_N + x1c];
        float v = (v00 * (1.f - fx) + v10 * fx) * (1.f - fy)
                + (v01 * (1.f - fx) + v11 * fx) * fy;
        gup[((size_t)(b * 2 + c)) * OUT_N * OUT_N + (size_t)oy * OUT_N + ox] = v;
    }
}

// grid_sample bilinear via CONTIGUOUS DMA-staged row bands.
// Block = 4 full-width output rows x CPB channels. Per channel: one
// contiguous 16 KB fetch (8 rows x 512) via 4 global_load_lds calls/wave,
// LDS gather, dwordx2 nontemporal stores. Counted vmcnt, raw barriers.
__global__ __launch_bounds__(256) void sample_kernel(const float* __restrict__ x,
                                                     const float* __restrict__ gup,
                                                     float* __restrict__ out) {
    __shared__ float tile[2 * BUFS];   // 33,280 B

    int bid = (int)blockIdx.x;
    // 4096 blocks; chunk 512 -> XCD k owns batch k; row-groups sweep fastest.
    bid = (bid & 7) * 512 + (bid >> 3);
    int b  = bid >> 9;
    int cg = (bid >> 7) & 3;
    int rg = bid & 127;
    int ty = rg * STH;
    int c0 = cg * CPB;

    int t  = threadIdx.x;
    int r  = t >> 6;          // output row 0..3 within the band
    int cb = (t & 63) * 2;    // column pair base

    // ---- per-thread DMA source offsets (channel-invariant, contiguous) ----
    // slot = k*256 + t: srow = 2k + (t>>7), scol = (t&127)*4.
    int goff[4];
    {
        int baserow = ty - 2 + (t >> 7);
        int scol = (t & 127) * 4;
        #pragma unroll
        for (int k = 0; k < 4; ++k) {
            int rr = baserow + 2 * k;
            rr = rr < 0 ? 0 : (rr > OUT_N - 1 ? OUT_N - 1 : rr);
            goff[k] = rr * OUT_N + scol;
        }
    }
    int wb0 = (t & ~63);       // wave-uniform slot base

    // ---- per-px bilinear weights + LDS base indices (channel-invariant) ----
    // Thread's 8 px: ox = 128*k + cb + h, oy = ty + r.
    float w00[8], w10[8], w01[8], w11[8];
    int lbase[8];
    int oy = ty + r;
    {
        size_t gplane = (size_t)OUT_N * OUT_N;
        size_t grow = (size_t)(b * 2) * gplane + (size_t)oy * OUT_N;
        float by = -1.0f + (float)oy * (2.0f / 511.0f);
        #pragma unroll
        for (int k = 0; k < 4; ++k) {
            #pragma unroll
            for (int h = 0; h < 2; ++h) {
                int j = k * 2 + h;
                int ox = 128 * k + cb + h;
                float gxu = gup[grow + ox];
                float gyu = gup[grow + ox + gplane];
                float bx = -1.0f + (float)ox * (2.0f / 511.0f);
                float gx = (49.0f * bx + gxu) * 0.02f;
                float gy = (49.0f * by + gyu) * 0.02f;
                float pxf = (gx + 1.0f) * 255.5f;  // in [0,511]
                float pyf = (gy + 1.0f) * 255.5f;
                float fx0 = floorf(pxf), fy0 = floorf(pyf);
                int x0 = (int)fx0, y0 = (int)fy0;
                float fx = pxf - fx0, fy = pyf - fy0;
                w00[j] = (1.f - fx) * (1.f - fy);
                w10[j] = fx * (1.f - fy);
                w01[j] = (1.f - fx) * fy;
                w11[j] = fx * fy;
                lbase[j] = (y0 - (ty - 2)) * SCOLS + x0;   // slot row 2..6
            }
        }
    }

    size_t plane = (size_t)OUT_N * OUT_N;
    const float* xb = x + ((size_t)b * CHAN + c0) * plane;
    float* ob = out + ((size_t)b * CHAN + c0) * plane;
    size_t orow = (size_t)oy * OUT_N;

    #define STAGE(c, bufIdx)                                                     \
        do {                                                                     \
            const float* xc_ = xb + (size_t)(c) * plane;                         \
            _Pragma("unroll")                                                    \
            for (int k_ = 0; k_ < 4; ++k_)                                       \
                GLD16(xc_ + goff[k_],                                            \
                      &tile[(bufIdx) * BUFS + (k_ * 256 + wb0) * 4]);            \
        } while (0)

    STAGE(0, 0);
    STAGE(1, 1);

    for (int c = 0; c < CPB; ++c) {
        // Counted wait for stage(c): younger ops are stage(c+1) [4] and
        // stores(c-1) [4] (stores issue in the gather phase).
        // c=0: only stage(1) -> 4.  c=CPB-1: only stores(c-1) -> 4.  else 8.
        if (c == 0 || c == CPB - 1) asm volatile("s_waitcnt vmcnt(4)" ::: "memory");
        else                        asm volatile("s_waitcnt vmcnt(8)" ::: "memory");
        __builtin_amdgcn_s_barrier();          // all waves' c-loads landed
        __builtin_amdgcn_sched_barrier(0);

        const float* tb_ = &tile[(c & 1) * BUFS];
        float* oc = ob + (size_t)c * plane;
        #pragma unroll
        for (int k = 0; k < 4; ++k) {
            float vv0, vv1;
            {
                int j = k * 2;
                int lb = lbase[j];
                vv0 = w00[j] * tb_[lb] + w10[j] * tb_[lb + 1]
                    + w01[j] * tb_[lb + SCOLS] + w11[j] * tb_[lb + SCOLS + 1];
            }
            {
                int j = k * 2 + 1;
                int lb = lbase[j];
                vv1 = w00[j] * tb_[lb] + w10[j] * tb_[lb + 1]
                    + w01[j] * tb_[lb + SCOLS] + w11[j] * tb_[lb + SCOLS + 1];
            }
            v2f st; st.x = vv0; st.y = vv1;
            __builtin_nontemporal_store(st, (v2f*)(oc + orow + cb + 128 * k));
        }

        __builtin_amdgcn_sched_barrier(0);
        __builtin_amdgcn_s_barrier();          // all waves done reading buf[c&1]
        __builtin_amdgcn_sched_barrier(0);

        if (c + 2 < CPB) STAGE(c + 2, c & 1);  // DMA overwrite now safe
    }
    #undef STAGE
}

extern "C" void kernel_launch(void* const* d_in, const int* in_sizes, int n_in,
                              void* d_out, int out_size, void* d_ws, size_t ws_size,
                              hipStream_t stream) {
    (void)in_sizes; (void)n_in; (void)d_ws; (void)ws_size; (void)out_size;
    const float* x  = (const float*)d_in[0];   // (8,32,512,512)
    const float* xs = (const float*)d_in[1];   // (8,1,256,256)
    // d_in[2] = gauss_kernel: recomputed analytically (separable form).

    float* out = (float*)d_out;
    const size_t XS_OUT = (size_t)BATCH * CHAN * OUT_N * OUT_N;  // 67,108,864
    float* gup = out + XS_OUT;  // output 1: grid_up (8,2,512,512)

    // Scratch lives in the x_sampled region of d_out; fully overwritten by
    // sample_kernel (which runs after its consumers).
    float* H    = out;                     // 8*4*316*256 = 2,588,672 floats
    float* g256 = out + 4u * 1024 * 1024;  // 8*2*256*256 = 1,048,576 floats

    hipLaunchKernelGGL(hpass_kernel, dim3(BATCH * GLOB_N), dim3(256), 0, stream, xs, H);
    hipLaunchKernelGGL(vpass_kernel, dim3(BATCH * GRID_N), dim3(256), 0, stream, H, g256);
    hipLaunchKernelGGL(upsample_kernel, dim3(BATCH * OUT_N * OUT_N / 256), dim3(256), 0, stream,
                       g256, gup);
    const int SBLOCKS = BATCH * (CHAN / CPB) * (OUT_N / STH);   // 4096
    hipLaunchKernelGGL(sample_kernel, dim3(SBLOCKS), dim3(256), 0, stream, x, gup, out);
}